// Round 2
// baseline (1197.182 us; speedup 1.0000x reference)
//
#include <hip/hip_runtime.h>

#define N_NODES 50000
#define HIDDEN  128
#define N_EDGES 600000

// ---------------- threefry2x32 (JAX-exact, key = (0,42)) ----------------
__device__ __forceinline__ unsigned rotl32(unsigned v, int r) {
  return (v << r) | (v >> (32 - r));
}

__device__ __forceinline__ void threefry2x32(unsigned x0, unsigned x1,
                                             unsigned& o0, unsigned& o1) {
  const unsigned ks0 = 0u, ks1 = 42u;
  const unsigned ks2 = ks0 ^ ks1 ^ 0x1BD11BDAu;
  const unsigned ks[3] = {ks0, ks1, ks2};
  const int rot[2][4] = {{13, 15, 26, 6}, {17, 29, 16, 24}};
  x0 += ks0; x1 += ks1;
#pragma unroll
  for (int i = 0; i < 5; ++i) {
#pragma unroll
    for (int j = 0; j < 4; ++j) {
      x0 += x1;
      x1 = rotl32(x1, rot[i & 1][j]);
      x1 ^= x0;
    }
    x0 += ks[(i + 1) % 3];
    x1 += ks[(i + 2) % 3] + (unsigned)(i + 1);
  }
  o0 = x0; o1 = x1;
}

// JAX threefry_partitionable=True (default since jax 0.4.36) random_bits:
// per element c: (o0,o1) = threefry2x32(key, (hi64(c)=0, lo32(c)=c));
// 32-bit word = o0 ^ o1. uniform = ((bits>>9)|0x3f800000)-1; mask = u<0.75.
__device__ __forceinline__ float col_mask(int c) {
  unsigned o0, o1;
  threefry2x32(0u, (unsigned)c, o0, o1);
  unsigned bits = o0 ^ o1;
  float u = __uint_as_float((bits >> 9) | 0x3f800000u) - 1.0f;
  return (u < 0.75f) ? 1.0f : 0.0f;
}

__device__ __forceinline__ float rlane(float v, int l) {
  return __int_as_float(__builtin_amdgcn_readlane(__float_as_int(v), l));
}

// ---------------- scatter-add: agg[dst] += x[src] ----------------
// 32 lanes per edge, float4 per lane.
__global__ __launch_bounds__(256) void scatter_kernel(
    const int* __restrict__ ei, const float* __restrict__ x,
    float* __restrict__ agg) {
  long long gid = (long long)blockIdx.x * blockDim.x + threadIdx.x;
  int e = (int)(gid >> 5);
  if (e >= N_EDGES) return;
  int sub = ((int)gid & 31) * 4;
  int src = ei[e];
  int dst = ei[N_EDGES + e];
  const float4 v = *reinterpret_cast<const float4*>(x + src * HIDDEN + sub);
  float* p = agg + dst * HIDDEN + sub;
  atomicAdd(p + 0, v.x);
  atomicAdd(p + 1, v.y);
  atomicAdd(p + 2, v.z);
  atomicAdd(p + 3, v.w);
}

// ---------------- fused mask + MLP, in-place on io (= d_out) ----------------
// io holds agg on entry; h0 = mask*(x+agg); out = relu(h0@W1+b1)@W2+b2.
// One wave handles 2 nodes per iteration; each lane owns cols (2l, 2l+1).
__global__ __launch_bounds__(512) void mlp_kernel(
    const float* __restrict__ x, float* __restrict__ io,
    const float* __restrict__ W1, const float* __restrict__ b1,
    const float* __restrict__ W2, const float* __restrict__ b2) {
  __shared__ float W1s[HIDDEN * HIDDEN];  // 64 KB
  __shared__ float W2s[HIDDEN * HIDDEN];  // 64 KB

  const int tid = threadIdx.x;
#pragma unroll
  for (int i = 0; i < 8; ++i) {
    int idx = (i * 512 + tid) * 4;
    *reinterpret_cast<float4*>(W1s + idx) =
        *reinterpret_cast<const float4*>(W1 + idx);
    *reinterpret_cast<float4*>(W2s + idx) =
        *reinterpret_cast<const float4*>(W2 + idx);
  }

  const int lane = tid & 63;
  const int wave = tid >> 6;
  const int c0 = 2 * lane, c1 = 2 * lane + 1;

  const float m0 = col_mask(c0);
  const float m1 = col_mask(c1);
  const float bb1x = b1[c0], bb1y = b1[c1];
  const float bb2x = b2[c0], bb2y = b2[c1];

  __syncthreads();

  const int gwave = blockIdx.x * 8 + wave;
  const int nwaves = gridDim.x * 8;

  for (int pr = gwave; pr < N_NODES / 2; pr += nwaves) {
    const int baseA = (2 * pr) * HIDDEN;
    const int baseB = baseA + HIDDEN;

    float2 xA = *reinterpret_cast<const float2*>(x + baseA + c0);
    float2 gA = *reinterpret_cast<const float2*>(io + baseA + c0);
    float2 xB = *reinterpret_cast<const float2*>(x + baseB + c0);
    float2 gB = *reinterpret_cast<const float2*>(io + baseB + c0);

    float hA0 = m0 * (xA.x + gA.x), hA1 = m1 * (xA.y + gA.y);
    float hB0 = m0 * (xB.x + gB.x), hB1 = m1 * (xB.y + gB.y);

    float aA0 = bb1x, aA1 = bb1y, aB0 = bb1x, aB1 = bb1y;
#pragma unroll
    for (int k = 0; k < HIDDEN; ++k) {
      const int sl = k >> 1;
      float hkA = (k & 1) ? rlane(hA1, sl) : rlane(hA0, sl);
      float hkB = (k & 1) ? rlane(hB1, sl) : rlane(hB0, sl);
      float2 w = *reinterpret_cast<const float2*>(W1s + k * HIDDEN + c0);
      aA0 = fmaf(hkA, w.x, aA0);
      aA1 = fmaf(hkA, w.y, aA1);
      aB0 = fmaf(hkB, w.x, aB0);
      aB1 = fmaf(hkB, w.y, aB1);
    }
    aA0 = fmaxf(aA0, 0.0f); aA1 = fmaxf(aA1, 0.0f);
    aB0 = fmaxf(aB0, 0.0f); aB1 = fmaxf(aB1, 0.0f);

    float oA0 = bb2x, oA1 = bb2y, oB0 = bb2x, oB1 = bb2y;
#pragma unroll
    for (int k = 0; k < HIDDEN; ++k) {
      const int sl = k >> 1;
      float hkA = (k & 1) ? rlane(aA1, sl) : rlane(aA0, sl);
      float hkB = (k & 1) ? rlane(aB1, sl) : rlane(aB0, sl);
      float2 w = *reinterpret_cast<const float2*>(W2s + k * HIDDEN + c0);
      oA0 = fmaf(hkA, w.x, oA0);
      oA1 = fmaf(hkA, w.y, oA1);
      oB0 = fmaf(hkB, w.x, oB0);
      oB1 = fmaf(hkB, w.y, oB1);
    }

    *reinterpret_cast<float2*>(io + baseA + c0) = make_float2(oA0, oA1);
    *reinterpret_cast<float2*>(io + baseB + c0) = make_float2(oB0, oB1);
  }
}

extern "C" void kernel_launch(void* const* d_in, const int* in_sizes, int n_in,
                              void* d_out, int out_size, void* d_ws,
                              size_t ws_size, hipStream_t stream) {
  (void)in_sizes; (void)n_in; (void)out_size; (void)d_ws; (void)ws_size;
  const float* x  = (const float*)d_in[0];
  const int*   ei = (const int*)d_in[1];
  const float* W1 = (const float*)d_in[2];
  const float* b1 = (const float*)d_in[3];
  const float* W2 = (const float*)d_in[4];
  const float* b2 = (const float*)d_in[5];
  float* out = (float*)d_out;

  // d_out doubles as the aggregation buffer (in-place row-wise MLP after).
  hipMemsetAsync(out, 0, (size_t)N_NODES * HIDDEN * sizeof(float), stream);

  const long long total = (long long)N_EDGES * 32;
  const int sblocks = (int)((total + 255) / 256);
  scatter_kernel<<<sblocks, 256, 0, stream>>>(ei, x, out);

  mlp_kernel<<<256, 512, 0, stream>>>(x, out, W1, b1, W2, b2);
}

// Round 3
// 434.741 us; speedup vs baseline: 2.7538x; 2.7538x over previous
//
#include <hip/hip_runtime.h>

#define N_NODES 50000
#define HIDDEN  128
#define N_EDGES 600000

// ---------------- threefry2x32 (JAX-exact, key = (0,42)) ----------------
__device__ __forceinline__ unsigned rotl32(unsigned v, int r) {
  return (v << r) | (v >> (32 - r));
}

__device__ __forceinline__ void threefry2x32(unsigned x0, unsigned x1,
                                             unsigned& o0, unsigned& o1) {
  const unsigned ks0 = 0u, ks1 = 42u;
  const unsigned ks2 = ks0 ^ ks1 ^ 0x1BD11BDAu;
  const unsigned ks[3] = {ks0, ks1, ks2};
  const int rot[2][4] = {{13, 15, 26, 6}, {17, 29, 16, 24}};
  x0 += ks0; x1 += ks1;
#pragma unroll
  for (int i = 0; i < 5; ++i) {
#pragma unroll
    for (int j = 0; j < 4; ++j) {
      x0 += x1;
      x1 = rotl32(x1, rot[i & 1][j]);
      x1 ^= x0;
    }
    x0 += ks[(i + 1) % 3];
    x1 += ks[(i + 2) % 3] + (unsigned)(i + 1);
  }
  o0 = x0; o1 = x1;
}

// JAX threefry_partitionable random_bits: bits[c] = o0^o1 of
// threefry(key=(0,42), counter=(0,c)); uniform = ((bits>>9)|0x3f800000)-1.
__device__ __forceinline__ float col_mask(int c) {
  unsigned o0, o1;
  threefry2x32(0u, (unsigned)c, o0, o1);
  unsigned bits = o0 ^ o1;
  float u = __uint_as_float((bits >> 9) | 0x3f800000u) - 1.0f;
  return (u < 0.75f) ? 1.0f : 0.0f;
}

__device__ __forceinline__ float rlane(float v, int l) {
  return __int_as_float(__builtin_amdgcn_readlane(__float_as_int(v), l));
}

// ---------------- CSR build ----------------
__global__ __launch_bounds__(256) void hist_kernel(const int* __restrict__ ei,
                                                   int* __restrict__ deg) {
  int e = blockIdx.x * blockDim.x + threadIdx.x;
  if (e >= N_EDGES) return;
  atomicAdd(deg + ei[N_EDGES + e], 1);
}

// Single-block exclusive scan of deg[50000] -> offs[50001]; pos = copy of offs.
__global__ __launch_bounds__(1024) void scan_kernel(const int* __restrict__ deg,
                                                    int* __restrict__ offs,
                                                    int* __restrict__ pos) {
  __shared__ int ssum[1024];
  const int t = threadIdx.x;
  const int CH = 49;  // 1024*49 = 50176 >= 50000
  const int base = t * CH;
  int s = 0;
#pragma unroll 1
  for (int i = 0; i < CH; ++i) {
    int idx = base + i;
    if (idx < N_NODES) s += deg[idx];
  }
  ssum[t] = s;
  __syncthreads();
  int v = s;
  for (int off = 1; off < 1024; off <<= 1) {
    int add = (t >= off) ? ssum[t - off] : 0;
    __syncthreads();
    v += add;
    ssum[t] = v;
    __syncthreads();
  }
  int run = v - s;  // exclusive offset of this thread's chunk
#pragma unroll 1
  for (int i = 0; i < CH; ++i) {
    int idx = base + i;
    if (idx < N_NODES) {
      offs[idx] = run;
      pos[idx] = run;
      run += deg[idx];
    }
  }
  if (t == 1023) offs[N_NODES] = v;  // total = N_EDGES
}

__global__ __launch_bounds__(256) void fill_kernel(const int* __restrict__ ei,
                                                   int* __restrict__ pos,
                                                   int* __restrict__ csr) {
  int e = blockIdx.x * blockDim.x + threadIdx.x;
  if (e >= N_EDGES) return;
  int src = ei[e];
  int dst = ei[N_EDGES + e];
  int p = atomicAdd(pos + dst, 1);
  csr[p] = src;
}

// ---------------- gather: agg[n] = sum over in-neighbors of x[nbr] ----------
// One wave per node; lane owns cols (2l, 2l+1).
__global__ __launch_bounds__(256) void gather_kernel(
    const int* __restrict__ offs, const int* __restrict__ csr,
    const float* __restrict__ x, float* __restrict__ agg) {
  int wid = (blockIdx.x * blockDim.x + threadIdx.x) >> 6;
  if (wid >= N_NODES) return;
  int lane = threadIdx.x & 63;
  int c0 = lane * 2;
  int s = offs[wid], e = offs[wid + 1];
  float accx = 0.f, accy = 0.f;
  for (int j = s; j < e; ++j) {
    int nbr = csr[j];
    float2 v = *reinterpret_cast<const float2*>(x + (size_t)nbr * HIDDEN + c0);
    accx += v.x;
    accy += v.y;
  }
  *reinterpret_cast<float2*>(agg + (size_t)wid * HIDDEN + c0) =
      make_float2(accx, accy);
}

// ---------------- fallback scatter (if ws too small) ----------------
__global__ __launch_bounds__(256) void scatter_kernel(
    const int* __restrict__ ei, const float* __restrict__ x,
    float* __restrict__ agg) {
  long long gid = (long long)blockIdx.x * blockDim.x + threadIdx.x;
  int e = (int)(gid >> 5);
  if (e >= N_EDGES) return;
  int sub = ((int)gid & 31) * 4;
  int src = ei[e];
  int dst = ei[N_EDGES + e];
  const float4 v = *reinterpret_cast<const float4*>(x + src * HIDDEN + sub);
  float* p = agg + dst * HIDDEN + sub;
  atomicAdd(p + 0, v.x);
  atomicAdd(p + 1, v.y);
  atomicAdd(p + 2, v.z);
  atomicAdd(p + 3, v.w);
}

// ---------------- fused mask + MLP, in-place on io (= d_out) ----------------
__global__ __launch_bounds__(512) void mlp_kernel(
    const float* __restrict__ x, float* __restrict__ io,
    const float* __restrict__ W1, const float* __restrict__ b1,
    const float* __restrict__ W2, const float* __restrict__ b2) {
  __shared__ float W1s[HIDDEN * HIDDEN];  // 64 KB
  __shared__ float W2s[HIDDEN * HIDDEN];  // 64 KB

  const int tid = threadIdx.x;
#pragma unroll
  for (int i = 0; i < 8; ++i) {
    int idx = (i * 512 + tid) * 4;
    *reinterpret_cast<float4*>(W1s + idx) =
        *reinterpret_cast<const float4*>(W1 + idx);
    *reinterpret_cast<float4*>(W2s + idx) =
        *reinterpret_cast<const float4*>(W2 + idx);
  }

  const int lane = tid & 63;
  const int wave = tid >> 6;
  const int c0 = 2 * lane, c1 = 2 * lane + 1;

  const float m0 = col_mask(c0);
  const float m1 = col_mask(c1);
  const float bb1x = b1[c0], bb1y = b1[c1];
  const float bb2x = b2[c0], bb2y = b2[c1];

  __syncthreads();

  const int gwave = blockIdx.x * 8 + wave;
  const int nwaves = gridDim.x * 8;

  for (int pr = gwave; pr < N_NODES / 2; pr += nwaves) {
    const int baseA = (2 * pr) * HIDDEN;
    const int baseB = baseA + HIDDEN;

    float2 xA = *reinterpret_cast<const float2*>(x + baseA + c0);
    float2 gA = *reinterpret_cast<const float2*>(io + baseA + c0);
    float2 xB = *reinterpret_cast<const float2*>(x + baseB + c0);
    float2 gB = *reinterpret_cast<const float2*>(io + baseB + c0);

    float hA0 = m0 * (xA.x + gA.x), hA1 = m1 * (xA.y + gA.y);
    float hB0 = m0 * (xB.x + gB.x), hB1 = m1 * (xB.y + gB.y);

    float aA0 = bb1x, aA1 = bb1y, aB0 = bb1x, aB1 = bb1y;
#pragma unroll
    for (int k = 0; k < HIDDEN; ++k) {
      const int sl = k >> 1;
      float hkA = (k & 1) ? rlane(hA1, sl) : rlane(hA0, sl);
      float hkB = (k & 1) ? rlane(hB1, sl) : rlane(hB0, sl);
      float2 w = *reinterpret_cast<const float2*>(W1s + k * HIDDEN + c0);
      aA0 = fmaf(hkA, w.x, aA0);
      aA1 = fmaf(hkA, w.y, aA1);
      aB0 = fmaf(hkB, w.x, aB0);
      aB1 = fmaf(hkB, w.y, aB1);
    }
    aA0 = fmaxf(aA0, 0.0f); aA1 = fmaxf(aA1, 0.0f);
    aB0 = fmaxf(aB0, 0.0f); aB1 = fmaxf(aB1, 0.0f);

    float oA0 = bb2x, oA1 = bb2y, oB0 = bb2x, oB1 = bb2y;
#pragma unroll
    for (int k = 0; k < HIDDEN; ++k) {
      const int sl = k >> 1;
      float hkA = (k & 1) ? rlane(aA1, sl) : rlane(aA0, sl);
      float hkB = (k & 1) ? rlane(aB1, sl) : rlane(aB0, sl);
      float2 w = *reinterpret_cast<const float2*>(W2s + k * HIDDEN + c0);
      oA0 = fmaf(hkA, w.x, oA0);
      oA1 = fmaf(hkA, w.y, oA1);
      oB0 = fmaf(hkB, w.x, oB0);
      oB1 = fmaf(hkB, w.y, oB1);
    }

    *reinterpret_cast<float2*>(io + baseA + c0) = make_float2(oA0, oA1);
    *reinterpret_cast<float2*>(io + baseB + c0) = make_float2(oB0, oB1);
  }
}

extern "C" void kernel_launch(void* const* d_in, const int* in_sizes, int n_in,
                              void* d_out, int out_size, void* d_ws,
                              size_t ws_size, hipStream_t stream) {
  (void)in_sizes; (void)n_in; (void)out_size;
  const float* x  = (const float*)d_in[0];
  const int*   ei = (const int*)d_in[1];
  const float* W1 = (const float*)d_in[2];
  const float* b1 = (const float*)d_in[3];
  const float* W2 = (const float*)d_in[4];
  const float* b2 = (const float*)d_in[5];
  float* out = (float*)d_out;

  // ws layout: deg[50000] | offs[50001] | pos[50000] | csr[600000]  (ints)
  const size_t need = (size_t)(N_NODES + (N_NODES + 1) + N_NODES + N_EDGES) * 4;

  if (ws_size >= need) {
    int* deg  = (int*)d_ws;
    int* offs = deg + N_NODES;
    int* pos  = offs + N_NODES + 1;
    int* csr  = pos + N_NODES;

    hipMemsetAsync(deg, 0, (size_t)N_NODES * 4, stream);
    hist_kernel<<<(N_EDGES + 255) / 256, 256, 0, stream>>>(ei, deg);
    scan_kernel<<<1, 1024, 0, stream>>>(deg, offs, pos);
    fill_kernel<<<(N_EDGES + 255) / 256, 256, 0, stream>>>(ei, pos, csr);
    gather_kernel<<<(N_NODES * 64 + 255) / 256, 256, 0, stream>>>(offs, csr, x,
                                                                  out);
  } else {
    // Fallback: atomic scatter directly into d_out.
    hipMemsetAsync(out, 0, (size_t)N_NODES * HIDDEN * sizeof(float), stream);
    const long long total = (long long)N_EDGES * 32;
    scatter_kernel<<<(int)((total + 255) / 256), 256, 0, stream>>>(ei, x, out);
  }

  mlp_kernel<<<256, 512, 0, stream>>>(x, out, W1, b1, W2, b2);
}

// Round 4
// 269.498 us; speedup vs baseline: 4.4423x; 1.6132x over previous
//
#include <hip/hip_runtime.h>

#define N_NODES 50000
#define HIDDEN  128
#define N_EDGES 600000
#define BR      32   // rows per block in fused kernel

typedef __attribute__((ext_vector_type(8))) short short8v;
typedef __attribute__((ext_vector_type(4))) float f32x4;

// ---------------- threefry2x32 (JAX-exact, key = (0,42)) ----------------
__device__ __forceinline__ unsigned rotl32(unsigned v, int r) {
  return (v << r) | (v >> (32 - r));
}

__device__ __forceinline__ void threefry2x32(unsigned x0, unsigned x1,
                                             unsigned& o0, unsigned& o1) {
  const unsigned ks0 = 0u, ks1 = 42u;
  const unsigned ks2 = ks0 ^ ks1 ^ 0x1BD11BDAu;
  const unsigned ks[3] = {ks0, ks1, ks2};
  const int rot[2][4] = {{13, 15, 26, 6}, {17, 29, 16, 24}};
  x0 += ks0; x1 += ks1;
#pragma unroll
  for (int i = 0; i < 5; ++i) {
#pragma unroll
    for (int j = 0; j < 4; ++j) {
      x0 += x1;
      x1 = rotl32(x1, rot[i & 1][j]);
      x1 ^= x0;
    }
    x0 += ks[(i + 1) % 3];
    x1 += ks[(i + 2) % 3] + (unsigned)(i + 1);
  }
  o0 = x0; o1 = x1;
}

// JAX threefry_partitionable random_bits: bits[c] = o0^o1 of
// threefry(key=(0,42), counter=(0,c)); uniform = ((bits>>9)|0x3f800000)-1.
__device__ __forceinline__ float col_mask(int c) {
  unsigned o0, o1;
  threefry2x32(0u, (unsigned)c, o0, o1);
  unsigned bits = o0 ^ o1;
  float u = __uint_as_float((bits >> 9) | 0x3f800000u) - 1.0f;
  return (u < 0.75f) ? 1.0f : 0.0f;
}

__device__ __forceinline__ unsigned short f2bf(float f) {
  unsigned u = __float_as_uint(f);
  u += 0x7fffu + ((u >> 16) & 1u);  // round-to-nearest-even
  return (unsigned short)(u >> 16);
}

__device__ __forceinline__ float rlane(float v, int l) {
  return __int_as_float(__builtin_amdgcn_readlane(__float_as_int(v), l));
}

// ---------------- CSR build ----------------
__global__ __launch_bounds__(256) void hist_kernel(const int* __restrict__ ei,
                                                   int* __restrict__ deg) {
  int e = blockIdx.x * blockDim.x + threadIdx.x;
  if (e >= N_EDGES) return;
  atomicAdd(deg + ei[N_EDGES + e], 1);
}

__global__ __launch_bounds__(1024) void scan_kernel(const int* __restrict__ deg,
                                                    int* __restrict__ offs,
                                                    int* __restrict__ pos) {
  __shared__ int ssum[1024];
  const int t = threadIdx.x;
  const int CH = 49;  // 1024*49 = 50176 >= 50000
  const int base = t * CH;
  int s = 0;
#pragma unroll 1
  for (int i = 0; i < CH; ++i) {
    int idx = base + i;
    if (idx < N_NODES) s += deg[idx];
  }
  ssum[t] = s;
  __syncthreads();
  int v = s;
  for (int off = 1; off < 1024; off <<= 1) {
    int add = (t >= off) ? ssum[t - off] : 0;
    __syncthreads();
    v += add;
    ssum[t] = v;
    __syncthreads();
  }
  int run = v - s;
#pragma unroll 1
  for (int i = 0; i < CH; ++i) {
    int idx = base + i;
    if (idx < N_NODES) {
      offs[idx] = run;
      pos[idx] = run;
      run += deg[idx];
    }
  }
  if (t == 1023) offs[N_NODES] = v;
}

__global__ __launch_bounds__(256) void fill_kernel(const int* __restrict__ ei,
                                                   int* __restrict__ pos,
                                                   int* __restrict__ csr) {
  int e = blockIdx.x * blockDim.x + threadIdx.x;
  if (e >= N_EDGES) return;
  int src = ei[e];
  int dst = ei[N_EDGES + e];
  int p = atomicAdd(pos + dst, 1);
  csr[p] = src;
}

// ---------------- weight prep: Wt[col][k] = bf16(W[k][col]) ----------------
__global__ __launch_bounds__(256) void prep_w(const float* __restrict__ W1,
                                              const float* __restrict__ W2,
                                              unsigned short* __restrict__ Wt1,
                                              unsigned short* __restrict__ Wt2) {
  int t = blockIdx.x * blockDim.x + threadIdx.x;
  if (t >= HIDDEN * HIDDEN) return;
  int col = t >> 7, k = t & 127;
  Wt1[t] = f2bf(W1[k * HIDDEN + col]);
  Wt2[t] = f2bf(W2[k * HIDDEN + col]);
}

// ---------------- fused gather + mask + MLP (bf16 MFMA) ----------------
// Block: 32 node-rows, 256 threads (4 waves). Wave w gathers rows [8w,8w+8)
// into H1 (XOR-swizzled bf16 LDS), then computes output cols [32w, 32w+32).
__global__ __launch_bounds__(256) void fused_kernel(
    const int* __restrict__ offs, const int* __restrict__ csr,
    const float* __restrict__ x, const unsigned short* __restrict__ Wt1,
    const unsigned short* __restrict__ Wt2, const float* __restrict__ b1,
    const float* __restrict__ b2, float* __restrict__ out) {
  __shared__ unsigned short H1[BR * HIDDEN];  // 8 KB, swizzled
  __shared__ unsigned short H2[BR * HIDDEN];  // 8 KB, swizzled

  const int tid = threadIdx.x;
  const int lane = tid & 63;
  const int wave = tid >> 6;
  const int base = blockIdx.x * BR;
  const int c0 = lane * 2;

  // ---- phase 1: gather + mask -> H1 (bf16) ----
  const float m0 = col_mask(c0), m1 = col_mask(c0 + 1);
#pragma unroll 1
  for (int i = 0; i < 8; ++i) {
    const int node = base + wave * 8 + i;
    float ax = 0.f, ay = 0.f;
    if (node < N_NODES) {
      const float2 own =
          *reinterpret_cast<const float2*>(x + (size_t)node * HIDDEN + c0);
      ax = own.x; ay = own.y;
      const int s = offs[node], e = offs[node + 1];
      int j = s;
      for (; j + 4 <= e; j += 4) {
        int n0 = csr[j], n1 = csr[j + 1], n2 = csr[j + 2], n3 = csr[j + 3];
        float2 v0 = *reinterpret_cast<const float2*>(x + (size_t)n0 * HIDDEN + c0);
        float2 v1 = *reinterpret_cast<const float2*>(x + (size_t)n1 * HIDDEN + c0);
        float2 v2 = *reinterpret_cast<const float2*>(x + (size_t)n2 * HIDDEN + c0);
        float2 v3 = *reinterpret_cast<const float2*>(x + (size_t)n3 * HIDDEN + c0);
        ax += v0.x + v1.x + v2.x + v3.x;
        ay += v0.y + v1.y + v2.y + v3.y;
      }
      for (; j < e; ++j) {
        int nb = csr[j];
        float2 v = *reinterpret_cast<const float2*>(x + (size_t)nb * HIDDEN + c0);
        ax += v.x; ay += v.y;
      }
    }
    const int row = wave * 8 + i;
    unsigned hx = (unsigned)f2bf(m0 * ax) | ((unsigned)f2bf(m1 * ay) << 16);
    const int byte = (row * 256 + c0 * 2) ^ ((row & 7) << 4);
    *reinterpret_cast<unsigned*>(reinterpret_cast<char*>(H1) + byte) = hx;
  }
  __syncthreads();

  // ---- phase 2: GEMM1 (H1 @ Wt1 + b1, relu) -> H2 ----
  const int colbase = wave * 32;  // 2 col-tiles per wave
  float bias1[2], bias2[2];
#pragma unroll
  for (int c = 0; c < 2; ++c) {
    bias1[c] = b1[colbase + c * 16 + (lane & 15)];
    bias2[c] = b2[colbase + c * 16 + (lane & 15)];
  }

  f32x4 acc[2][2] = {};
#pragma unroll
  for (int kt = 0; kt < 4; ++kt) {
    short8v a[2], b[2];
#pragma unroll
    for (int r = 0; r < 2; ++r) {
      int row = r * 16 + (lane & 15);
      int byte = (row * 256 + kt * 64 + (lane >> 4) * 16) ^ ((row & 7) << 4);
      a[r] = *reinterpret_cast<const short8v*>(
          reinterpret_cast<const char*>(H1) + byte);
    }
#pragma unroll
    for (int c = 0; c < 2; ++c) {
      int col = colbase + c * 16 + (lane & 15);
      b[c] = *reinterpret_cast<const short8v*>(
          reinterpret_cast<const char*>(Wt1) + col * 256 + kt * 64 +
          (lane >> 4) * 16);
    }
#pragma unroll
    for (int r = 0; r < 2; ++r)
#pragma unroll
      for (int c = 0; c < 2; ++c)
        acc[r][c] = __builtin_amdgcn_mfma_f32_16x16x32_bf16(a[r], b[c],
                                                            acc[r][c], 0, 0, 0);
  }
#pragma unroll
  for (int r = 0; r < 2; ++r)
#pragma unroll
    for (int c = 0; c < 2; ++c)
#pragma unroll
      for (int q = 0; q < 4; ++q) {
        int row = r * 16 + (lane >> 4) * 4 + q;
        int col = colbase + c * 16 + (lane & 15);
        float v = fmaxf(acc[r][c][q] + bias1[c], 0.f);
        int byte = (row * 256 + col * 2) ^ ((row & 7) << 4);
        *reinterpret_cast<unsigned short*>(reinterpret_cast<char*>(H2) + byte) =
            f2bf(v);
      }
  __syncthreads();

  // ---- phase 3: GEMM2 (H2 @ Wt2 + b2) -> out ----
  f32x4 acc2[2][2] = {};
#pragma unroll
  for (int kt = 0; kt < 4; ++kt) {
    short8v a[2], b[2];
#pragma unroll
    for (int r = 0; r < 2; ++r) {
      int row = r * 16 + (lane & 15);
      int byte = (row * 256 + kt * 64 + (lane >> 4) * 16) ^ ((row & 7) << 4);
      a[r] = *reinterpret_cast<const short8v*>(
          reinterpret_cast<const char*>(H2) + byte);
    }
#pragma unroll
    for (int c = 0; c < 2; ++c) {
      int col = colbase + c * 16 + (lane & 15);
      b[c] = *reinterpret_cast<const short8v*>(
          reinterpret_cast<const char*>(Wt2) + col * 256 + kt * 64 +
          (lane >> 4) * 16);
    }
#pragma unroll
    for (int r = 0; r < 2; ++r)
#pragma unroll
      for (int c = 0; c < 2; ++c)
        acc2[r][c] = __builtin_amdgcn_mfma_f32_16x16x32_bf16(
            a[r], b[c], acc2[r][c], 0, 0, 0);
  }
#pragma unroll
  for (int r = 0; r < 2; ++r)
#pragma unroll
    for (int c = 0; c < 2; ++c)
#pragma unroll
      for (int q = 0; q < 4; ++q) {
        int row = base + r * 16 + (lane >> 4) * 4 + q;
        if (row < N_NODES) {
          int col = colbase + c * 16 + (lane & 15);
          out[(size_t)row * HIDDEN + col] = acc2[r][c][q] + bias2[c];
        }
      }
}

// ---------------- Tier-B fallback kernels (f32 path, round-3 proven) -------
__global__ __launch_bounds__(256) void gather_kernel(
    const int* __restrict__ offs, const int* __restrict__ csr,
    const float* __restrict__ x, float* __restrict__ agg) {
  int wid = (blockIdx.x * blockDim.x + threadIdx.x) >> 6;
  if (wid >= N_NODES) return;
  int lane = threadIdx.x & 63;
  int c0 = lane * 2;
  int s = offs[wid], e = offs[wid + 1];
  float accx = 0.f, accy = 0.f;
  for (int j = s; j < e; ++j) {
    int nbr = csr[j];
    float2 v = *reinterpret_cast<const float2*>(x + (size_t)nbr * HIDDEN + c0);
    accx += v.x;
    accy += v.y;
  }
  *reinterpret_cast<float2*>(agg + (size_t)wid * HIDDEN + c0) =
      make_float2(accx, accy);
}

__global__ __launch_bounds__(256) void scatter_kernel(
    const int* __restrict__ ei, const float* __restrict__ x,
    float* __restrict__ agg) {
  long long gid = (long long)blockIdx.x * blockDim.x + threadIdx.x;
  int e = (int)(gid >> 5);
  if (e >= N_EDGES) return;
  int sub = ((int)gid & 31) * 4;
  int src = ei[e];
  int dst = ei[N_EDGES + e];
  const float4 v = *reinterpret_cast<const float4*>(x + src * HIDDEN + sub);
  float* p = agg + dst * HIDDEN + sub;
  atomicAdd(p + 0, v.x);
  atomicAdd(p + 1, v.y);
  atomicAdd(p + 2, v.z);
  atomicAdd(p + 3, v.w);
}

__global__ __launch_bounds__(512) void mlp_kernel(
    const float* __restrict__ x, float* __restrict__ io,
    const float* __restrict__ W1, const float* __restrict__ b1,
    const float* __restrict__ W2, const float* __restrict__ b2) {
  __shared__ float W1s[HIDDEN * HIDDEN];
  __shared__ float W2s[HIDDEN * HIDDEN];

  const int tid = threadIdx.x;
#pragma unroll
  for (int i = 0; i < 8; ++i) {
    int idx = (i * 512 + tid) * 4;
    *reinterpret_cast<float4*>(W1s + idx) =
        *reinterpret_cast<const float4*>(W1 + idx);
    *reinterpret_cast<float4*>(W2s + idx) =
        *reinterpret_cast<const float4*>(W2 + idx);
  }

  const int lane = tid & 63;
  const int wave = tid >> 6;
  const int c0 = 2 * lane, c1 = 2 * lane + 1;

  const float m0 = col_mask(c0);
  const float m1 = col_mask(c1);
  const float bb1x = b1[c0], bb1y = b1[c1];
  const float bb2x = b2[c0], bb2y = b2[c1];

  __syncthreads();

  const int gwave = blockIdx.x * 8 + wave;
  const int nwaves = gridDim.x * 8;

  for (int pr = gwave; pr < N_NODES / 2; pr += nwaves) {
    const int baseA = (2 * pr) * HIDDEN;
    const int baseB = baseA + HIDDEN;

    float2 xA = *reinterpret_cast<const float2*>(x + baseA + c0);
    float2 gA = *reinterpret_cast<const float2*>(io + baseA + c0);
    float2 xB = *reinterpret_cast<const float2*>(x + baseB + c0);
    float2 gB = *reinterpret_cast<const float2*>(io + baseB + c0);

    float hA0 = m0 * (xA.x + gA.x), hA1 = m1 * (xA.y + gA.y);
    float hB0 = m0 * (xB.x + gB.x), hB1 = m1 * (xB.y + gB.y);

    float aA0 = bb1x, aA1 = bb1y, aB0 = bb1x, aB1 = bb1y;
#pragma unroll
    for (int k = 0; k < HIDDEN; ++k) {
      const int sl = k >> 1;
      float hkA = (k & 1) ? rlane(hA1, sl) : rlane(hA0, sl);
      float hkB = (k & 1) ? rlane(hB1, sl) : rlane(hB0, sl);
      float2 w = *reinterpret_cast<const float2*>(W1s + k * HIDDEN + c0);
      aA0 = fmaf(hkA, w.x, aA0);
      aA1 = fmaf(hkA, w.y, aA1);
      aB0 = fmaf(hkB, w.x, aB0);
      aB1 = fmaf(hkB, w.y, aB1);
    }
    aA0 = fmaxf(aA0, 0.0f); aA1 = fmaxf(aA1, 0.0f);
    aB0 = fmaxf(aB0, 0.0f); aB1 = fmaxf(aB1, 0.0f);

    float oA0 = bb2x, oA1 = bb2y, oB0 = bb2x, oB1 = bb2y;
#pragma unroll
    for (int k = 0; k < HIDDEN; ++k) {
      const int sl = k >> 1;
      float hkA = (k & 1) ? rlane(aA1, sl) : rlane(aA0, sl);
      float hkB = (k & 1) ? rlane(aB1, sl) : rlane(aB0, sl);
      float2 w = *reinterpret_cast<const float2*>(W2s + k * HIDDEN + c0);
      oA0 = fmaf(hkA, w.x, oA0);
      oA1 = fmaf(hkA, w.y, oA1);
      oB0 = fmaf(hkB, w.x, oB0);
      oB1 = fmaf(hkB, w.y, oB1);
    }

    *reinterpret_cast<float2*>(io + baseA + c0) = make_float2(oA0, oA1);
    *reinterpret_cast<float2*>(io + baseB + c0) = make_float2(oB0, oB1);
  }
}

extern "C" void kernel_launch(void* const* d_in, const int* in_sizes, int n_in,
                              void* d_out, int out_size, void* d_ws,
                              size_t ws_size, hipStream_t stream) {
  (void)in_sizes; (void)n_in; (void)out_size;
  const float* x  = (const float*)d_in[0];
  const int*   ei = (const int*)d_in[1];
  const float* W1 = (const float*)d_in[2];
  const float* b1 = (const float*)d_in[3];
  const float* W2 = (const float*)d_in[4];
  const float* b2 = (const float*)d_in[5];
  float* out = (float*)d_out;

  // ws layout: deg[50000] offs[50001] pos[50000] csr[600000] Wt1 Wt2
  const size_t csr_need = (size_t)(N_NODES + (N_NODES + 1) + N_NODES + N_EDGES) * 4;
  const size_t full_need = csr_need + 2 * (size_t)HIDDEN * HIDDEN * 2;

  if (ws_size >= csr_need) {
    int* deg  = (int*)d_ws;
    int* offs = deg + N_NODES;
    int* pos  = offs + N_NODES + 1;
    int* csr  = pos + N_NODES;

    hipMemsetAsync(deg, 0, (size_t)N_NODES * 4, stream);
    hist_kernel<<<(N_EDGES + 255) / 256, 256, 0, stream>>>(ei, deg);
    scan_kernel<<<1, 1024, 0, stream>>>(deg, offs, pos);
    fill_kernel<<<(N_EDGES + 255) / 256, 256, 0, stream>>>(ei, pos, csr);

    if (ws_size >= full_need) {
      // Tier A: fused bf16-MFMA path.
      unsigned short* Wt1 = (unsigned short*)(csr + N_EDGES);
      unsigned short* Wt2 = Wt1 + HIDDEN * HIDDEN;
      prep_w<<<(HIDDEN * HIDDEN + 255) / 256, 256, 0, stream>>>(W1, W2, Wt1, Wt2);
      fused_kernel<<<(N_NODES + BR - 1) / BR, 256, 0, stream>>>(
          offs, csr, x, Wt1, Wt2, b1, b2, out);
    } else {
      // Tier B: f32 gather + rlane MLP.
      gather_kernel<<<(N_NODES * 64 + 255) / 256, 256, 0, stream>>>(offs, csr,
                                                                    x, out);
      mlp_kernel<<<256, 512, 0, stream>>>(x, out, W1, b1, W2, b2);
    }
  } else {
    // Tier C: atomic scatter + rlane MLP.
    hipMemsetAsync(out, 0, (size_t)N_NODES * HIDDEN * sizeof(float), stream);
    const long long total = (long long)N_EDGES * 32;
    scatter_kernel<<<(int)((total + 255) / 256), 256, 0, stream>>>(ei, x, out);
    mlp_kernel<<<256, 512, 0, stream>>>(x, out, W1, b1, W2, b2);
  }
}

// Round 5
// 153.879 us; speedup vs baseline: 7.7800x; 1.7514x over previous
//
#include <hip/hip_runtime.h>

#define N_NODES 50000
#define HIDDEN  128
#define N_EDGES 600000
#define BR      32                 // rows per block in fused kernel
#define NB      ((N_NODES + 255) / 256)  // 196 scan blocks

typedef __attribute__((ext_vector_type(8))) short short8v;
typedef __attribute__((ext_vector_type(4))) float f32x4;

// ---------------- threefry2x32 (JAX-exact, key = (0,42)) ----------------
__device__ __forceinline__ unsigned rotl32(unsigned v, int r) {
  return (v << r) | (v >> (32 - r));
}

__device__ __forceinline__ void threefry2x32(unsigned x0, unsigned x1,
                                             unsigned& o0, unsigned& o1) {
  const unsigned ks0 = 0u, ks1 = 42u;
  const unsigned ks2 = ks0 ^ ks1 ^ 0x1BD11BDAu;
  const unsigned ks[3] = {ks0, ks1, ks2};
  const int rot[2][4] = {{13, 15, 26, 6}, {17, 29, 16, 24}};
  x0 += ks0; x1 += ks1;
#pragma unroll
  for (int i = 0; i < 5; ++i) {
#pragma unroll
    for (int j = 0; j < 4; ++j) {
      x0 += x1;
      x1 = rotl32(x1, rot[i & 1][j]);
      x1 ^= x0;
    }
    x0 += ks[(i + 1) % 3];
    x1 += ks[(i + 2) % 3] + (unsigned)(i + 1);
  }
  o0 = x0; o1 = x1;
}

// JAX threefry_partitionable random_bits: bits[c] = o0^o1 of
// threefry(key=(0,42), counter=(0,c)); uniform = ((bits>>9)|0x3f800000)-1.
__device__ __forceinline__ float col_mask(int c) {
  unsigned o0, o1;
  threefry2x32(0u, (unsigned)c, o0, o1);
  unsigned bits = o0 ^ o1;
  float u = __uint_as_float((bits >> 9) | 0x3f800000u) - 1.0f;
  return (u < 0.75f) ? 1.0f : 0.0f;
}

__device__ __forceinline__ unsigned short f2bf(float f) {
  unsigned u = __float_as_uint(f);
  u += 0x7fffu + ((u >> 16) & 1u);  // round-to-nearest-even
  return (unsigned short)(u >> 16);
}

__device__ __forceinline__ float rlane(float v, int l) {
  return __int_as_float(__builtin_amdgcn_readlane(__float_as_int(v), l));
}

// ---------------- CSR build ----------------
__global__ __launch_bounds__(256) void hist_kernel(const int* __restrict__ ei,
                                                   int* __restrict__ deg) {
  int e = blockIdx.x * blockDim.x + threadIdx.x;
  if (e >= N_EDGES) return;
  atomicAdd(deg + ei[N_EDGES + e], 1);
}

// Two-level scan, stage A: per-block (256-chunk) degree sums.
__global__ __launch_bounds__(256) void scanA_kernel(const int* __restrict__ deg,
                                                    int* __restrict__ bsum) {
  int idx = blockIdx.x * 256 + threadIdx.x;
  int v = (idx < N_NODES) ? deg[idx] : 0;
#pragma unroll
  for (int off = 32; off; off >>= 1) v += __shfl_down(v, off, 64);
  __shared__ int ws4[4];
  if ((threadIdx.x & 63) == 0) ws4[threadIdx.x >> 6] = v;
  __syncthreads();
  if (threadIdx.x == 0) bsum[blockIdx.x] = ws4[0] + ws4[1] + ws4[2] + ws4[3];
}

// Stage B: exclusive scan of the NB block sums (NB=196 <= 256).
__global__ __launch_bounds__(256) void scanB_kernel(const int* __restrict__ bsum,
                                                    int* __restrict__ bpre,
                                                    int* __restrict__ offs) {
  __shared__ int s[256];
  const int t = threadIdx.x;
  int v = (t < NB) ? bsum[t] : 0;
  s[t] = v;
  __syncthreads();
  int acc = v;
  for (int off = 1; off < 256; off <<= 1) {
    int add = (t >= off) ? s[t - off] : 0;
    __syncthreads();
    acc += add;
    s[t] = acc;
    __syncthreads();
  }
  if (t < NB) bpre[t] = acc - v;  // exclusive prefix
  if (t == 0) offs[N_NODES] = N_EDGES;
}

// Stage C: per-block local exclusive scan + block prefix -> offs, pos.
__global__ __launch_bounds__(256) void scanC_kernel(const int* __restrict__ deg,
                                                    const int* __restrict__ bpre,
                                                    int* __restrict__ offs,
                                                    int* __restrict__ pos) {
  __shared__ int s[256];
  const int t = threadIdx.x;
  const int idx = blockIdx.x * 256 + t;
  int v = (idx < N_NODES) ? deg[idx] : 0;
  s[t] = v;
  __syncthreads();
  int acc = v;
  for (int off = 1; off < 256; off <<= 1) {
    int add = (t >= off) ? s[t - off] : 0;
    __syncthreads();
    acc += add;
    s[t] = acc;
    __syncthreads();
  }
  if (idx < N_NODES) {
    int o = bpre[blockIdx.x] + acc - v;
    offs[idx] = o;
    pos[idx] = o;
  }
}

__global__ __launch_bounds__(256) void fill_kernel(const int* __restrict__ ei,
                                                   int* __restrict__ pos,
                                                   int* __restrict__ csr) {
  int e = blockIdx.x * blockDim.x + threadIdx.x;
  if (e >= N_EDGES) return;
  int src = ei[e];
  int dst = ei[N_EDGES + e];
  int p = atomicAdd(pos + dst, 1);
  csr[p] = src;
}

// ---------------- weight prep: Wt[col][k] = bf16(W[k][col]) ----------------
__global__ __launch_bounds__(256) void prep_w(const float* __restrict__ W1,
                                              const float* __restrict__ W2,
                                              unsigned short* __restrict__ Wt1,
                                              unsigned short* __restrict__ Wt2) {
  int t = blockIdx.x * blockDim.x + threadIdx.x;
  if (t >= HIDDEN * HIDDEN) return;
  int col = t >> 7, k = t & 127;
  Wt1[t] = f2bf(W1[k * HIDDEN + col]);
  Wt2[t] = f2bf(W2[k * HIDDEN + col]);
}

// ---------------- fused gather + mask + MLP (bf16 MFMA) ----------------
// Block: 32 node-rows, 256 threads (4 waves). Wave w gathers rows [8w,8w+8)
// into H1 (XOR-swizzled bf16 LDS), then computes output cols [32w, 32w+32).
__global__ __launch_bounds__(256) void fused_kernel(
    const int* __restrict__ offs, const int* __restrict__ csr,
    const float* __restrict__ x, const unsigned short* __restrict__ Wt1,
    const unsigned short* __restrict__ Wt2, const float* __restrict__ b1,
    const float* __restrict__ b2, float* __restrict__ out) {
  __shared__ unsigned short H1[BR * HIDDEN];  // 8 KB, swizzled
  __shared__ unsigned short H2[BR * HIDDEN];  // 8 KB, swizzled

  const int tid = threadIdx.x;
  const int lane = tid & 63;
  const int wave = tid >> 6;
  const int base = blockIdx.x * BR;
  const int c0 = lane * 2;

  // ---- phase 1: gather + mask -> H1 (bf16) ----
  const float m0 = col_mask(c0), m1 = col_mask(c0 + 1);
#pragma unroll 1
  for (int i = 0; i < 8; ++i) {
    const int node = base + wave * 8 + i;
    float ax = 0.f, ay = 0.f;
    if (node < N_NODES) {
      const float2 own =
          *reinterpret_cast<const float2*>(x + (size_t)node * HIDDEN + c0);
      ax = own.x; ay = own.y;
      const int s = offs[node], e = offs[node + 1];
      int j = s;
      for (; j + 4 <= e; j += 4) {
        int n0 = csr[j], n1 = csr[j + 1], n2 = csr[j + 2], n3 = csr[j + 3];
        float2 v0 = *reinterpret_cast<const float2*>(x + (size_t)n0 * HIDDEN + c0);
        float2 v1 = *reinterpret_cast<const float2*>(x + (size_t)n1 * HIDDEN + c0);
        float2 v2 = *reinterpret_cast<const float2*>(x + (size_t)n2 * HIDDEN + c0);
        float2 v3 = *reinterpret_cast<const float2*>(x + (size_t)n3 * HIDDEN + c0);
        ax += v0.x + v1.x + v2.x + v3.x;
        ay += v0.y + v1.y + v2.y + v3.y;
      }
      for (; j < e; ++j) {
        int nb = csr[j];
        float2 v = *reinterpret_cast<const float2*>(x + (size_t)nb * HIDDEN + c0);
        ax += v.x; ay += v.y;
      }
    }
    const int row = wave * 8 + i;
    unsigned hx = (unsigned)f2bf(m0 * ax) | ((unsigned)f2bf(m1 * ay) << 16);
    const int byte = (row * 256 + c0 * 2) ^ ((row & 7) << 4);
    *reinterpret_cast<unsigned*>(reinterpret_cast<char*>(H1) + byte) = hx;
  }
  __syncthreads();

  // ---- phase 2: GEMM1 (H1 @ Wt1 + b1, relu) -> H2 ----
  const int colbase = wave * 32;  // 2 col-tiles per wave
  float bias1[2], bias2[2];
#pragma unroll
  for (int c = 0; c < 2; ++c) {
    bias1[c] = b1[colbase + c * 16 + (lane & 15)];
    bias2[c] = b2[colbase + c * 16 + (lane & 15)];
  }

  f32x4 acc[2][2] = {};
#pragma unroll
  for (int kt = 0; kt < 4; ++kt) {
    short8v a[2], b[2];
#pragma unroll
    for (int r = 0; r < 2; ++r) {
      int row = r * 16 + (lane & 15);
      int byte = (row * 256 + kt * 64 + (lane >> 4) * 16) ^ ((row & 7) << 4);
      a[r] = *reinterpret_cast<const short8v*>(
          reinterpret_cast<const char*>(H1) + byte);
    }
#pragma unroll
    for (int c = 0; c < 2; ++c) {
      int col = colbase + c * 16 + (lane & 15);
      b[c] = *reinterpret_cast<const short8v*>(
          reinterpret_cast<const char*>(Wt1) + col * 256 + kt * 64 +
          (lane >> 4) * 16);
    }
#pragma unroll
    for (int r = 0; r < 2; ++r)
#pragma unroll
      for (int c = 0; c < 2; ++c)
        acc[r][c] = __builtin_amdgcn_mfma_f32_16x16x32_bf16(a[r], b[c],
                                                            acc[r][c], 0, 0, 0);
  }
#pragma unroll
  for (int r = 0; r < 2; ++r)
#pragma unroll
    for (int c = 0; c < 2; ++c)
#pragma unroll
      for (int q = 0; q < 4; ++q) {
        int row = r * 16 + (lane >> 4) * 4 + q;
        int col = colbase + c * 16 + (lane & 15);
        float v = fmaxf(acc[r][c][q] + bias1[c], 0.f);
        int byte = (row * 256 + col * 2) ^ ((row & 7) << 4);
        *reinterpret_cast<unsigned short*>(reinterpret_cast<char*>(H2) + byte) =
            f2bf(v);
      }
  __syncthreads();

  // ---- phase 3: GEMM2 (H2 @ Wt2 + b2) -> out ----
  f32x4 acc2[2][2] = {};
#pragma unroll
  for (int kt = 0; kt < 4; ++kt) {
    short8v a[2], b[2];
#pragma unroll
    for (int r = 0; r < 2; ++r) {
      int row = r * 16 + (lane & 15);
      int byte = (row * 256 + kt * 64 + (lane >> 4) * 16) ^ ((row & 7) << 4);
      a[r] = *reinterpret_cast<const short8v*>(
          reinterpret_cast<const char*>(H2) + byte);
    }
#pragma unroll
    for (int c = 0; c < 2; ++c) {
      int col = colbase + c * 16 + (lane & 15);
      b[c] = *reinterpret_cast<const short8v*>(
          reinterpret_cast<const char*>(Wt2) + col * 256 + kt * 64 +
          (lane >> 4) * 16);
    }
#pragma unroll
    for (int r = 0; r < 2; ++r)
#pragma unroll
      for (int c = 0; c < 2; ++c)
        acc2[r][c] = __builtin_amdgcn_mfma_f32_16x16x32_bf16(
            a[r], b[c], acc2[r][c], 0, 0, 0);
  }
#pragma unroll
  for (int r = 0; r < 2; ++r)
#pragma unroll
    for (int c = 0; c < 2; ++c)
#pragma unroll
      for (int q = 0; q < 4; ++q) {
        int row = base + r * 16 + (lane >> 4) * 4 + q;
        if (row < N_NODES) {
          int col = colbase + c * 16 + (lane & 15);
          out[(size_t)row * HIDDEN + col] = acc2[r][c][q] + bias2[c];
        }
      }
}

// ---------------- Tier-B fallback kernels (f32 path, round-3 proven) -------
__global__ __launch_bounds__(256) void gather_kernel(
    const int* __restrict__ offs, const int* __restrict__ csr,
    const float* __restrict__ x, float* __restrict__ agg) {
  int wid = (blockIdx.x * blockDim.x + threadIdx.x) >> 6;
  if (wid >= N_NODES) return;
  int lane = threadIdx.x & 63;
  int c0 = lane * 2;
  int s = offs[wid], e = offs[wid + 1];
  float accx = 0.f, accy = 0.f;
  for (int j = s; j < e; ++j) {
    int nbr = csr[j];
    float2 v = *reinterpret_cast<const float2*>(x + (size_t)nbr * HIDDEN + c0);
    accx += v.x;
    accy += v.y;
  }
  *reinterpret_cast<float2*>(agg + (size_t)wid * HIDDEN + c0) =
      make_float2(accx, accy);
}

__global__ __launch_bounds__(256) void scatter_kernel(
    const int* __restrict__ ei, const float* __restrict__ x,
    float* __restrict__ agg) {
  long long gid = (long long)blockIdx.x * blockDim.x + threadIdx.x;
  int e = (int)(gid >> 5);
  if (e >= N_EDGES) return;
  int sub = ((int)gid & 31) * 4;
  int src = ei[e];
  int dst = ei[N_EDGES + e];
  const float4 v = *reinterpret_cast<const float4*>(x + src * HIDDEN + sub);
  float* p = agg + dst * HIDDEN + sub;
  atomicAdd(p + 0, v.x);
  atomicAdd(p + 1, v.y);
  atomicAdd(p + 2, v.z);
  atomicAdd(p + 3, v.w);
}

__global__ __launch_bounds__(512) void mlp_kernel(
    const float* __restrict__ x, float* __restrict__ io,
    const float* __restrict__ W1, const float* __restrict__ b1,
    const float* __restrict__ W2, const float* __restrict__ b2) {
  __shared__ float W1s[HIDDEN * HIDDEN];
  __shared__ float W2s[HIDDEN * HIDDEN];

  const int tid = threadIdx.x;
#pragma unroll
  for (int i = 0; i < 8; ++i) {
    int idx = (i * 512 + tid) * 4;
    *reinterpret_cast<float4*>(W1s + idx) =
        *reinterpret_cast<const float4*>(W1 + idx);
    *reinterpret_cast<float4*>(W2s + idx) =
        *reinterpret_cast<const float4*>(W2 + idx);
  }

  const int lane = tid & 63;
  const int wave = tid >> 6;
  const int c0 = 2 * lane, c1 = 2 * lane + 1;

  const float m0 = col_mask(c0);
  const float m1 = col_mask(c1);
  const float bb1x = b1[c0], bb1y = b1[c1];
  const float bb2x = b2[c0], bb2y = b2[c1];

  __syncthreads();

  const int gwave = blockIdx.x * 8 + wave;
  const int nwaves = gridDim.x * 8;

  for (int pr = gwave; pr < N_NODES / 2; pr += nwaves) {
    const int baseA = (2 * pr) * HIDDEN;
    const int baseB = baseA + HIDDEN;

    float2 xA = *reinterpret_cast<const float2*>(x + baseA + c0);
    float2 gA = *reinterpret_cast<const float2*>(io + baseA + c0);
    float2 xB = *reinterpret_cast<const float2*>(x + baseB + c0);
    float2 gB = *reinterpret_cast<const float2*>(io + baseB + c0);

    float hA0 = m0 * (xA.x + gA.x), hA1 = m1 * (xA.y + gA.y);
    float hB0 = m0 * (xB.x + gB.x), hB1 = m1 * (xB.y + gB.y);

    float aA0 = bb1x, aA1 = bb1y, aB0 = bb1x, aB1 = bb1y;
#pragma unroll
    for (int k = 0; k < HIDDEN; ++k) {
      const int sl = k >> 1;
      float hkA = (k & 1) ? rlane(hA1, sl) : rlane(hA0, sl);
      float hkB = (k & 1) ? rlane(hB1, sl) : rlane(hB0, sl);
      float2 w = *reinterpret_cast<const float2*>(W1s + k * HIDDEN + c0);
      aA0 = fmaf(hkA, w.x, aA0);
      aA1 = fmaf(hkA, w.y, aA1);
      aB0 = fmaf(hkB, w.x, aB0);
      aB1 = fmaf(hkB, w.y, aB1);
    }
    aA0 = fmaxf(aA0, 0.0f); aA1 = fmaxf(aA1, 0.0f);
    aB0 = fmaxf(aB0, 0.0f); aB1 = fmaxf(aB1, 0.0f);

    float oA0 = bb2x, oA1 = bb2y, oB0 = bb2x, oB1 = bb2y;
#pragma unroll
    for (int k = 0; k < HIDDEN; ++k) {
      const int sl = k >> 1;
      float hkA = (k & 1) ? rlane(aA1, sl) : rlane(aA0, sl);
      float hkB = (k & 1) ? rlane(aB1, sl) : rlane(aB0, sl);
      float2 w = *reinterpret_cast<const float2*>(W2s + k * HIDDEN + c0);
      oA0 = fmaf(hkA, w.x, oA0);
      oA1 = fmaf(hkA, w.y, oA1);
      oB0 = fmaf(hkB, w.x, oB0);
      oB1 = fmaf(hkB, w.y, oB1);
    }

    *reinterpret_cast<float2*>(io + baseA + c0) = make_float2(oA0, oA1);
    *reinterpret_cast<float2*>(io + baseB + c0) = make_float2(oB0, oB1);
  }
}

extern "C" void kernel_launch(void* const* d_in, const int* in_sizes, int n_in,
                              void* d_out, int out_size, void* d_ws,
                              size_t ws_size, hipStream_t stream) {
  (void)in_sizes; (void)n_in; (void)out_size;
  const float* x  = (const float*)d_in[0];
  const int*   ei = (const int*)d_in[1];
  const float* W1 = (const float*)d_in[2];
  const float* b1 = (const float*)d_in[3];
  const float* W2 = (const float*)d_in[4];
  const float* b2 = (const float*)d_in[5];
  float* out = (float*)d_out;

  // ws layout (ints): deg[N] offs[N+1] pos[N] csr[E] bsum[NB] bpre[NB] | Wt1 Wt2
  const size_t csr_need =
      (size_t)(N_NODES + (N_NODES + 1) + N_NODES + N_EDGES + 2 * NB) * 4;
  const size_t full_need = csr_need + 2 * (size_t)HIDDEN * HIDDEN * 2;

  if (ws_size >= csr_need) {
    int* deg  = (int*)d_ws;
    int* offs = deg + N_NODES;
    int* pos  = offs + N_NODES + 1;
    int* csr  = pos + N_NODES;
    int* bsum = csr + N_EDGES;
    int* bpre = bsum + NB;

    hipMemsetAsync(deg, 0, (size_t)N_NODES * 4, stream);
    hist_kernel<<<(N_EDGES + 255) / 256, 256, 0, stream>>>(ei, deg);
    scanA_kernel<<<NB, 256, 0, stream>>>(deg, bsum);
    scanB_kernel<<<1, 256, 0, stream>>>(bsum, bpre, offs);
    scanC_kernel<<<NB, 256, 0, stream>>>(deg, bpre, offs, pos);
    fill_kernel<<<(N_EDGES + 255) / 256, 256, 0, stream>>>(ei, pos, csr);

    if (ws_size >= full_need) {
      // Tier A: fused bf16-MFMA path.
      unsigned short* Wt1 = (unsigned short*)(bpre + NB);
      unsigned short* Wt2 = Wt1 + HIDDEN * HIDDEN;
      prep_w<<<(HIDDEN * HIDDEN + 255) / 256, 256, 0, stream>>>(W1, W2, Wt1, Wt2);
      fused_kernel<<<(N_NODES + BR - 1) / BR, 256, 0, stream>>>(
          offs, csr, x, Wt1, Wt2, b1, b2, out);
    } else {
      // Tier B: f32 gather + rlane MLP.
      gather_kernel<<<(N_NODES * 64 + 255) / 256, 256, 0, stream>>>(offs, csr,
                                                                    x, out);
      mlp_kernel<<<256, 512, 0, stream>>>(x, out, W1, b1, W2, b2);
    }
  } else {
    // Tier C: atomic scatter + rlane MLP.
    hipMemsetAsync(out, 0, (size_t)N_NODES * HIDDEN * sizeof(float), stream);
    const long long total = (long long)N_EDGES * 32;
    scatter_kernel<<<(int)((total + 255) / 256), 256, 0, stream>>>(ei, x, out);
    mlp_kernel<<<256, 512, 0, stream>>>(x, out, W1, b1, W2, b2);
  }
}

// Round 6
// 150.052 us; speedup vs baseline: 7.9785x; 1.0255x over previous
//
#include <hip/hip_runtime.h>

#define N_NODES 50000
#define HIDDEN  128
#define N_EDGES 600000
#define BR      32                 // rows per block in fused kernel
#define NB      ((N_NODES + 255) / 256)  // 196 scan blocks

typedef __attribute__((ext_vector_type(8))) short short8v;
typedef __attribute__((ext_vector_type(4))) float f32x4;

// ---------------- threefry2x32 (JAX-exact, key = (0,42)) ----------------
__device__ __forceinline__ unsigned rotl32(unsigned v, int r) {
  return (v << r) | (v >> (32 - r));
}

__device__ __forceinline__ void threefry2x32(unsigned x0, unsigned x1,
                                             unsigned& o0, unsigned& o1) {
  const unsigned ks0 = 0u, ks1 = 42u;
  const unsigned ks2 = ks0 ^ ks1 ^ 0x1BD11BDAu;
  const unsigned ks[3] = {ks0, ks1, ks2};
  const int rot[2][4] = {{13, 15, 26, 6}, {17, 29, 16, 24}};
  x0 += ks0; x1 += ks1;
#pragma unroll
  for (int i = 0; i < 5; ++i) {
#pragma unroll
    for (int j = 0; j < 4; ++j) {
      x0 += x1;
      x1 = rotl32(x1, rot[i & 1][j]);
      x1 ^= x0;
    }
    x0 += ks[(i + 1) % 3];
    x1 += ks[(i + 2) % 3] + (unsigned)(i + 1);
  }
  o0 = x0; o1 = x1;
}

// JAX threefry_partitionable random_bits: bits[c] = o0^o1 of
// threefry(key=(0,42), counter=(0,c)); uniform = ((bits>>9)|0x3f800000)-1.
__device__ __forceinline__ float col_mask(int c) {
  unsigned o0, o1;
  threefry2x32(0u, (unsigned)c, o0, o1);
  unsigned bits = o0 ^ o1;
  float u = __uint_as_float((bits >> 9) | 0x3f800000u) - 1.0f;
  return (u < 0.75f) ? 1.0f : 0.0f;
}

__device__ __forceinline__ unsigned short f2bf(float f) {
  unsigned u = __float_as_uint(f);
  u += 0x7fffu + ((u >> 16) & 1u);  // round-to-nearest-even
  return (unsigned short)(u >> 16);
}

__device__ __forceinline__ float bflo(unsigned u) {
  return __uint_as_float(u << 16);
}
__device__ __forceinline__ float bfhi(unsigned u) {
  return __uint_as_float(u & 0xffff0000u);
}

__device__ __forceinline__ float rlane(float v, int l) {
  return __int_as_float(__builtin_amdgcn_readlane(__float_as_int(v), l));
}

// ---------------- CSR build ----------------
__global__ __launch_bounds__(256) void hist_kernel(const int* __restrict__ ei,
                                                   int* __restrict__ deg) {
  int e = blockIdx.x * blockDim.x + threadIdx.x;
  if (e >= N_EDGES) return;
  atomicAdd(deg + ei[N_EDGES + e], 1);
}

// Two-level scan, stage A: per-block (256-chunk) degree sums.
__global__ __launch_bounds__(256) void scanA_kernel(const int* __restrict__ deg,
                                                    int* __restrict__ bsum) {
  int idx = blockIdx.x * 256 + threadIdx.x;
  int v = (idx < N_NODES) ? deg[idx] : 0;
#pragma unroll
  for (int off = 32; off; off >>= 1) v += __shfl_down(v, off, 64);
  __shared__ int ws4[4];
  if ((threadIdx.x & 63) == 0) ws4[threadIdx.x >> 6] = v;
  __syncthreads();
  if (threadIdx.x == 0) bsum[blockIdx.x] = ws4[0] + ws4[1] + ws4[2] + ws4[3];
}

// Stage B: exclusive scan of the NB block sums (NB=196 <= 256).
__global__ __launch_bounds__(256) void scanB_kernel(const int* __restrict__ bsum,
                                                    int* __restrict__ bpre,
                                                    int* __restrict__ offs) {
  __shared__ int s[256];
  const int t = threadIdx.x;
  int v = (t < NB) ? bsum[t] : 0;
  s[t] = v;
  __syncthreads();
  int acc = v;
  for (int off = 1; off < 256; off <<= 1) {
    int add = (t >= off) ? s[t - off] : 0;
    __syncthreads();
    acc += add;
    s[t] = acc;
    __syncthreads();
  }
  if (t < NB) bpre[t] = acc - v;  // exclusive prefix
  if (t == 0) offs[N_NODES] = N_EDGES;
}

// Stage C: per-block local exclusive scan + block prefix -> offs, pos.
__global__ __launch_bounds__(256) void scanC_kernel(const int* __restrict__ deg,
                                                    const int* __restrict__ bpre,
                                                    int* __restrict__ offs,
                                                    int* __restrict__ pos) {
  __shared__ int s[256];
  const int t = threadIdx.x;
  const int idx = blockIdx.x * 256 + t;
  int v = (idx < N_NODES) ? deg[idx] : 0;
  s[t] = v;
  __syncthreads();
  int acc = v;
  for (int off = 1; off < 256; off <<= 1) {
    int add = (t >= off) ? s[t - off] : 0;
    __syncthreads();
    acc += add;
    s[t] = acc;
    __syncthreads();
  }
  if (idx < N_NODES) {
    int o = bpre[blockIdx.x] + acc - v;
    offs[idx] = o;
    pos[idx] = o;
  }
}

__global__ __launch_bounds__(256) void fill_kernel(const int* __restrict__ ei,
                                                   int* __restrict__ pos,
                                                   int* __restrict__ csr) {
  int e = blockIdx.x * blockDim.x + threadIdx.x;
  if (e >= N_EDGES) return;
  int src = ei[e];
  int dst = ei[N_EDGES + e];
  int p = atomicAdd(pos + dst, 1);
  csr[p] = src;
}

// ---------------- prep: xb = bf16(mask .* x);  Wt = bf16(W^T) -------------
// One kernel: 3125 blocks x 256 threads; thread handles 8 xb elements.
// Threads with gid < 4096 additionally transpose 4 elements of each W.
__global__ __launch_bounds__(256) void prep_kernel(
    const float* __restrict__ x, const float* __restrict__ W1,
    const float* __restrict__ W2, unsigned short* __restrict__ xb,
    unsigned short* __restrict__ Wt1, unsigned short* __restrict__ Wt2) {
  __shared__ float msk[HIDDEN];
  if (threadIdx.x < HIDDEN) msk[threadIdx.x] = col_mask(threadIdx.x);
  __syncthreads();

  const int gid = blockIdx.x * 256 + threadIdx.x;
  const int e0 = gid * 8;  // 8 contiguous elements
  if (e0 < N_NODES * HIDDEN) {
    const int c0 = e0 & (HIDDEN - 1);
    const float4 v0 = *reinterpret_cast<const float4*>(x + e0);
    const float4 v1 = *reinterpret_cast<const float4*>(x + e0 + 4);
    unsigned short h[8];
    h[0] = f2bf(v0.x * msk[c0 + 0]);
    h[1] = f2bf(v0.y * msk[c0 + 1]);
    h[2] = f2bf(v0.z * msk[c0 + 2]);
    h[3] = f2bf(v0.w * msk[c0 + 3]);
    h[4] = f2bf(v1.x * msk[c0 + 4]);
    h[5] = f2bf(v1.y * msk[c0 + 5]);
    h[6] = f2bf(v1.z * msk[c0 + 6]);
    h[7] = f2bf(v1.w * msk[c0 + 7]);
    *reinterpret_cast<uint4*>(xb + e0) = *reinterpret_cast<uint4*>(h);
  }
  if (gid < HIDDEN * HIDDEN / 4) {
#pragma unroll
    for (int i = 0; i < 4; ++i) {
      int t = gid * 4 + i;           // Wt index
      int col = t >> 7, k = t & 127; // Wt[col][k] = W[k][col]
      Wt1[t] = f2bf(W1[k * HIDDEN + col]);
      Wt2[t] = f2bf(W2[k * HIDDEN + col]);
    }
  }
}

// ---------------- fused gather(bf16) + MLP (bf16 MFMA) ----------------
// Block: 32 node-rows, 256 threads (4 waves). Wave w gathers rows [8w,8w+8)
// from xb (pre-masked bf16) into H1 (XOR-swizzled LDS), then computes
// output cols [32w, 32w+32).
__global__ __launch_bounds__(256) void fused_xb_kernel(
    const int* __restrict__ offs, const int* __restrict__ csr,
    const unsigned short* __restrict__ xb,
    const unsigned short* __restrict__ Wt1,
    const unsigned short* __restrict__ Wt2, const float* __restrict__ b1,
    const float* __restrict__ b2, float* __restrict__ out) {
  __shared__ unsigned short H1[BR * HIDDEN];  // 8 KB, swizzled
  __shared__ unsigned short H2[BR * HIDDEN];  // 8 KB, swizzled

  const int tid = threadIdx.x;
  const int lane = tid & 63;
  const int wave = tid >> 6;
  const int base = blockIdx.x * BR;
  const int c0 = lane * 2;

  // ---- phase 1: gather (mask already baked into xb) -> H1 ----
#pragma unroll 1
  for (int i = 0; i < 8; ++i) {
    const int node = base + wave * 8 + i;
    float ax = 0.f, ay = 0.f;
    if (node < N_NODES) {
      unsigned own =
          *reinterpret_cast<const unsigned*>(xb + (size_t)node * HIDDEN + c0);
      ax = bflo(own);
      ay = bfhi(own);
      const int s = offs[node], e = offs[node + 1];
      int j = s;
      for (; j + 4 <= e; j += 4) {
        int n0 = csr[j], n1 = csr[j + 1], n2 = csr[j + 2], n3 = csr[j + 3];
        unsigned u0 = *reinterpret_cast<const unsigned*>(xb + (size_t)n0 * HIDDEN + c0);
        unsigned u1 = *reinterpret_cast<const unsigned*>(xb + (size_t)n1 * HIDDEN + c0);
        unsigned u2 = *reinterpret_cast<const unsigned*>(xb + (size_t)n2 * HIDDEN + c0);
        unsigned u3 = *reinterpret_cast<const unsigned*>(xb + (size_t)n3 * HIDDEN + c0);
        ax += bflo(u0) + bflo(u1) + bflo(u2) + bflo(u3);
        ay += bfhi(u0) + bfhi(u1) + bfhi(u2) + bfhi(u3);
      }
      for (; j < e; ++j) {
        int nb = csr[j];
        unsigned u = *reinterpret_cast<const unsigned*>(xb + (size_t)nb * HIDDEN + c0);
        ax += bflo(u);
        ay += bfhi(u);
      }
    }
    const int row = wave * 8 + i;
    unsigned hx = (unsigned)f2bf(ax) | ((unsigned)f2bf(ay) << 16);
    const int byte = (row * 256 + c0 * 2) ^ ((row & 7) << 4);
    *reinterpret_cast<unsigned*>(reinterpret_cast<char*>(H1) + byte) = hx;
  }
  __syncthreads();

  // ---- phase 2: GEMM1 (H1 @ Wt1 + b1, relu) -> H2 ----
  const int colbase = wave * 32;  // 2 col-tiles per wave
  float bias1[2], bias2[2];
#pragma unroll
  for (int c = 0; c < 2; ++c) {
    bias1[c] = b1[colbase + c * 16 + (lane & 15)];
    bias2[c] = b2[colbase + c * 16 + (lane & 15)];
  }

  f32x4 acc[2][2] = {};
#pragma unroll
  for (int kt = 0; kt < 4; ++kt) {
    short8v a[2], b[2];
#pragma unroll
    for (int r = 0; r < 2; ++r) {
      int row = r * 16 + (lane & 15);
      int byte = (row * 256 + kt * 64 + (lane >> 4) * 16) ^ ((row & 7) << 4);
      a[r] = *reinterpret_cast<const short8v*>(
          reinterpret_cast<const char*>(H1) + byte);
    }
#pragma unroll
    for (int c = 0; c < 2; ++c) {
      int col = colbase + c * 16 + (lane & 15);
      b[c] = *reinterpret_cast<const short8v*>(
          reinterpret_cast<const char*>(Wt1) + col * 256 + kt * 64 +
          (lane >> 4) * 16);
    }
#pragma unroll
    for (int r = 0; r < 2; ++r)
#pragma unroll
      for (int c = 0; c < 2; ++c)
        acc[r][c] = __builtin_amdgcn_mfma_f32_16x16x32_bf16(a[r], b[c],
                                                            acc[r][c], 0, 0, 0);
  }
#pragma unroll
  for (int r = 0; r < 2; ++r)
#pragma unroll
    for (int c = 0; c < 2; ++c)
#pragma unroll
      for (int q = 0; q < 4; ++q) {
        int row = r * 16 + (lane >> 4) * 4 + q;
        int col = colbase + c * 16 + (lane & 15);
        float v = fmaxf(acc[r][c][q] + bias1[c], 0.f);
        int byte = (row * 256 + col * 2) ^ ((row & 7) << 4);
        *reinterpret_cast<unsigned short*>(reinterpret_cast<char*>(H2) + byte) =
            f2bf(v);
      }
  __syncthreads();

  // ---- phase 3: GEMM2 (H2 @ Wt2 + b2) -> out ----
  f32x4 acc2[2][2] = {};
#pragma unroll
  for (int kt = 0; kt < 4; ++kt) {
    short8v a[2], b[2];
#pragma unroll
    for (int r = 0; r < 2; ++r) {
      int row = r * 16 + (lane & 15);
      int byte = (row * 256 + kt * 64 + (lane >> 4) * 16) ^ ((row & 7) << 4);
      a[r] = *reinterpret_cast<const short8v*>(
          reinterpret_cast<const char*>(H2) + byte);
    }
#pragma unroll
    for (int c = 0; c < 2; ++c) {
      int col = colbase + c * 16 + (lane & 15);
      b[c] = *reinterpret_cast<const short8v*>(
          reinterpret_cast<const char*>(Wt2) + col * 256 + kt * 64 +
          (lane >> 4) * 16);
    }
#pragma unroll
    for (int r = 0; r < 2; ++r)
#pragma unroll
      for (int c = 0; c < 2; ++c)
        acc2[r][c] = __builtin_amdgcn_mfma_f32_16x16x32_bf16(
            a[r], b[c], acc2[r][c], 0, 0, 0);
  }
#pragma unroll
  for (int r = 0; r < 2; ++r)
#pragma unroll
    for (int c = 0; c < 2; ++c)
#pragma unroll
      for (int q = 0; q < 4; ++q) {
        int row = base + r * 16 + (lane >> 4) * 4 + q;
        if (row < N_NODES) {
          int col = colbase + c * 16 + (lane & 15);
          out[(size_t)row * HIDDEN + col] = acc2[r][c][q] + bias2[c];
        }
      }
}

// ---------------- Tier A-old: f32-gather fused (round-5 proven) ------------
__global__ __launch_bounds__(256) void prep_w(const float* __restrict__ W1,
                                              const float* __restrict__ W2,
                                              unsigned short* __restrict__ Wt1,
                                              unsigned short* __restrict__ Wt2) {
  int t = blockIdx.x * blockDim.x + threadIdx.x;
  if (t >= HIDDEN * HIDDEN) return;
  int col = t >> 7, k = t & 127;
  Wt1[t] = f2bf(W1[k * HIDDEN + col]);
  Wt2[t] = f2bf(W2[k * HIDDEN + col]);
}

__global__ __launch_bounds__(256) void fused_kernel(
    const int* __restrict__ offs, const int* __restrict__ csr,
    const float* __restrict__ x, const unsigned short* __restrict__ Wt1,
    const unsigned short* __restrict__ Wt2, const float* __restrict__ b1,
    const float* __restrict__ b2, float* __restrict__ out) {
  __shared__ unsigned short H1[BR * HIDDEN];
  __shared__ unsigned short H2[BR * HIDDEN];

  const int tid = threadIdx.x;
  const int lane = tid & 63;
  const int wave = tid >> 6;
  const int base = blockIdx.x * BR;
  const int c0 = lane * 2;

  const float m0 = col_mask(c0), m1 = col_mask(c0 + 1);
#pragma unroll 1
  for (int i = 0; i < 8; ++i) {
    const int node = base + wave * 8 + i;
    float ax = 0.f, ay = 0.f;
    if (node < N_NODES) {
      const float2 own =
          *reinterpret_cast<const float2*>(x + (size_t)node * HIDDEN + c0);
      ax = own.x; ay = own.y;
      const int s = offs[node], e = offs[node + 1];
      int j = s;
      for (; j + 4 <= e; j += 4) {
        int n0 = csr[j], n1 = csr[j + 1], n2 = csr[j + 2], n3 = csr[j + 3];
        float2 v0 = *reinterpret_cast<const float2*>(x + (size_t)n0 * HIDDEN + c0);
        float2 v1 = *reinterpret_cast<const float2*>(x + (size_t)n1 * HIDDEN + c0);
        float2 v2 = *reinterpret_cast<const float2*>(x + (size_t)n2 * HIDDEN + c0);
        float2 v3 = *reinterpret_cast<const float2*>(x + (size_t)n3 * HIDDEN + c0);
        ax += v0.x + v1.x + v2.x + v3.x;
        ay += v0.y + v1.y + v2.y + v3.y;
      }
      for (; j < e; ++j) {
        int nb = csr[j];
        float2 v = *reinterpret_cast<const float2*>(x + (size_t)nb * HIDDEN + c0);
        ax += v.x; ay += v.y;
      }
    }
    const int row = wave * 8 + i;
    unsigned hx = (unsigned)f2bf(m0 * ax) | ((unsigned)f2bf(m1 * ay) << 16);
    const int byte = (row * 256 + c0 * 2) ^ ((row & 7) << 4);
    *reinterpret_cast<unsigned*>(reinterpret_cast<char*>(H1) + byte) = hx;
  }
  __syncthreads();

  const int colbase = wave * 32;
  float bias1[2], bias2[2];
#pragma unroll
  for (int c = 0; c < 2; ++c) {
    bias1[c] = b1[colbase + c * 16 + (lane & 15)];
    bias2[c] = b2[colbase + c * 16 + (lane & 15)];
  }

  f32x4 acc[2][2] = {};
#pragma unroll
  for (int kt = 0; kt < 4; ++kt) {
    short8v a[2], b[2];
#pragma unroll
    for (int r = 0; r < 2; ++r) {
      int row = r * 16 + (lane & 15);
      int byte = (row * 256 + kt * 64 + (lane >> 4) * 16) ^ ((row & 7) << 4);
      a[r] = *reinterpret_cast<const short8v*>(
          reinterpret_cast<const char*>(H1) + byte);
    }
#pragma unroll
    for (int c = 0; c < 2; ++c) {
      int col = colbase + c * 16 + (lane & 15);
      b[c] = *reinterpret_cast<const short8v*>(
          reinterpret_cast<const char*>(Wt1) + col * 256 + kt * 64 +
          (lane >> 4) * 16);
    }
#pragma unroll
    for (int r = 0; r < 2; ++r)
#pragma unroll
      for (int c = 0; c < 2; ++c)
        acc[r][c] = __builtin_amdgcn_mfma_f32_16x16x32_bf16(a[r], b[c],
                                                            acc[r][c], 0, 0, 0);
  }
#pragma unroll
  for (int r = 0; r < 2; ++r)
#pragma unroll
    for (int c = 0; c < 2; ++c)
#pragma unroll
      for (int q = 0; q < 4; ++q) {
        int row = r * 16 + (lane >> 4) * 4 + q;
        int col = colbase + c * 16 + (lane & 15);
        float v = fmaxf(acc[r][c][q] + bias1[c], 0.f);
        int byte = (row * 256 + col * 2) ^ ((row & 7) << 4);
        *reinterpret_cast<unsigned short*>(reinterpret_cast<char*>(H2) + byte) =
            f2bf(v);
      }
  __syncthreads();

  f32x4 acc2[2][2] = {};
#pragma unroll
  for (int kt = 0; kt < 4; ++kt) {
    short8v a[2], b[2];
#pragma unroll
    for (int r = 0; r < 2; ++r) {
      int row = r * 16 + (lane & 15);
      int byte = (row * 256 + kt * 64 + (lane >> 4) * 16) ^ ((row & 7) << 4);
      a[r] = *reinterpret_cast<const short8v*>(
          reinterpret_cast<const char*>(H2) + byte);
    }
#pragma unroll
    for (int c = 0; c < 2; ++c) {
      int col = colbase + c * 16 + (lane & 15);
      b[c] = *reinterpret_cast<const short8v*>(
          reinterpret_cast<const char*>(Wt2) + col * 256 + kt * 64 +
          (lane >> 4) * 16);
    }
#pragma unroll
    for (int r = 0; r < 2; ++r)
#pragma unroll
      for (int c = 0; c < 2; ++c)
        acc2[r][c] = __builtin_amdgcn_mfma_f32_16x16x32_bf16(
            a[r], b[c], acc2[r][c], 0, 0, 0);
  }
#pragma unroll
  for (int r = 0; r < 2; ++r)
#pragma unroll
    for (int c = 0; c < 2; ++c)
#pragma unroll
      for (int q = 0; q < 4; ++q) {
        int row = base + r * 16 + (lane >> 4) * 4 + q;
        if (row < N_NODES) {
          int col = colbase + c * 16 + (lane & 15);
          out[(size_t)row * HIDDEN + col] = acc2[r][c][q] + bias2[c];
        }
      }
}

// ---------------- Tier-B/C fallback kernels (round-3 proven) ---------------
__global__ __launch_bounds__(256) void gather_kernel(
    const int* __restrict__ offs, const int* __restrict__ csr,
    const float* __restrict__ x, float* __restrict__ agg) {
  int wid = (blockIdx.x * blockDim.x + threadIdx.x) >> 6;
  if (wid >= N_NODES) return;
  int lane = threadIdx.x & 63;
  int c0 = lane * 2;
  int s = offs[wid], e = offs[wid + 1];
  float accx = 0.f, accy = 0.f;
  for (int j = s; j < e; ++j) {
    int nbr = csr[j];
    float2 v = *reinterpret_cast<const float2*>(x + (size_t)nbr * HIDDEN + c0);
    accx += v.x;
    accy += v.y;
  }
  *reinterpret_cast<float2*>(agg + (size_t)wid * HIDDEN + c0) =
      make_float2(accx, accy);
}

__global__ __launch_bounds__(256) void scatter_kernel(
    const int* __restrict__ ei, const float* __restrict__ x,
    float* __restrict__ agg) {
  long long gid = (long long)blockIdx.x * blockDim.x + threadIdx.x;
  int e = (int)(gid >> 5);
  if (e >= N_EDGES) return;
  int sub = ((int)gid & 31) * 4;
  int src = ei[e];
  int dst = ei[N_EDGES + e];
  const float4 v = *reinterpret_cast<const float4*>(x + src * HIDDEN + sub);
  float* p = agg + dst * HIDDEN + sub;
  atomicAdd(p + 0, v.x);
  atomicAdd(p + 1, v.y);
  atomicAdd(p + 2, v.z);
  atomicAdd(p + 3, v.w);
}

__global__ __launch_bounds__(512) void mlp_kernel(
    const float* __restrict__ x, float* __restrict__ io,
    const float* __restrict__ W1, const float* __restrict__ b1,
    const float* __restrict__ W2, const float* __restrict__ b2) {
  __shared__ float W1s[HIDDEN * HIDDEN];
  __shared__ float W2s[HIDDEN * HIDDEN];

  const int tid = threadIdx.x;
#pragma unroll
  for (int i = 0; i < 8; ++i) {
    int idx = (i * 512 + tid) * 4;
    *reinterpret_cast<float4*>(W1s + idx) =
        *reinterpret_cast<const float4*>(W1 + idx);
    *reinterpret_cast<float4*>(W2s + idx) =
        *reinterpret_cast<const float4*>(W2 + idx);
  }

  const int lane = tid & 63;
  const int wave = tid >> 6;
  const int c0 = 2 * lane, c1 = 2 * lane + 1;

  const float m0 = col_mask(c0);
  const float m1 = col_mask(c1);
  const float bb1x = b1[c0], bb1y = b1[c1];
  const float bb2x = b2[c0], bb2y = b2[c1];

  __syncthreads();

  const int gwave = blockIdx.x * 8 + wave;
  const int nwaves = gridDim.x * 8;

  for (int pr = gwave; pr < N_NODES / 2; pr += nwaves) {
    const int baseA = (2 * pr) * HIDDEN;
    const int baseB = baseA + HIDDEN;

    float2 xA = *reinterpret_cast<const float2*>(x + baseA + c0);
    float2 gA = *reinterpret_cast<const float2*>(io + baseA + c0);
    float2 xB = *reinterpret_cast<const float2*>(x + baseB + c0);
    float2 gB = *reinterpret_cast<const float2*>(io + baseB + c0);

    float hA0 = m0 * (xA.x + gA.x), hA1 = m1 * (xA.y + gA.y);
    float hB0 = m0 * (xB.x + gB.x), hB1 = m1 * (xB.y + gB.y);

    float aA0 = bb1x, aA1 = bb1y, aB0 = bb1x, aB1 = bb1y;
#pragma unroll
    for (int k = 0; k < HIDDEN; ++k) {
      const int sl = k >> 1;
      float hkA = (k & 1) ? rlane(hA1, sl) : rlane(hA0, sl);
      float hkB = (k & 1) ? rlane(hB1, sl) : rlane(hB0, sl);
      float2 w = *reinterpret_cast<const float2*>(W1s + k * HIDDEN + c0);
      aA0 = fmaf(hkA, w.x, aA0);
      aA1 = fmaf(hkA, w.y, aA1);
      aB0 = fmaf(hkB, w.x, aB0);
      aB1 = fmaf(hkB, w.y, aB1);
    }
    aA0 = fmaxf(aA0, 0.0f); aA1 = fmaxf(aA1, 0.0f);
    aB0 = fmaxf(aB0, 0.0f); aB1 = fmaxf(aB1, 0.0f);

    float oA0 = bb2x, oA1 = bb2y, oB0 = bb2x, oB1 = bb2y;
#pragma unroll
    for (int k = 0; k < HIDDEN; ++k) {
      const int sl = k >> 1;
      float hkA = (k & 1) ? rlane(aA1, sl) : rlane(aA0, sl);
      float hkB = (k & 1) ? rlane(aB1, sl) : rlane(aB0, sl);
      float2 w = *reinterpret_cast<const float2*>(W2s + k * HIDDEN + c0);
      oA0 = fmaf(hkA, w.x, oA0);
      oA1 = fmaf(hkA, w.y, oA1);
      oB0 = fmaf(hkB, w.x, oB0);
      oB1 = fmaf(hkB, w.y, oB1);
    }

    *reinterpret_cast<float2*>(io + baseA + c0) = make_float2(oA0, oA1);
    *reinterpret_cast<float2*>(io + baseB + c0) = make_float2(oB0, oB1);
  }
}

extern "C" void kernel_launch(void* const* d_in, const int* in_sizes, int n_in,
                              void* d_out, int out_size, void* d_ws,
                              size_t ws_size, hipStream_t stream) {
  (void)in_sizes; (void)n_in; (void)out_size;
  const float* x  = (const float*)d_in[0];
  const int*   ei = (const int*)d_in[1];
  const float* W1 = (const float*)d_in[2];
  const float* b1 = (const float*)d_in[3];
  const float* W2 = (const float*)d_in[4];
  const float* b2 = (const float*)d_in[5];
  float* out = (float*)d_out;

  // ws layout (ints): deg[N] offs[N+1] pos[N] csr[E] bsum[NB] bpre[NB]
  //                   | Wt1 Wt2 (bf16) | xb (bf16, N*HIDDEN)
  const size_t csr_need =
      (size_t)(N_NODES + (N_NODES + 1) + N_NODES + N_EDGES + 2 * NB) * 4;
  const size_t wt_need = csr_need + 2 * (size_t)HIDDEN * HIDDEN * 2;
  const size_t xb_need = wt_need + (size_t)N_NODES * HIDDEN * 2;

  if (ws_size >= csr_need) {
    int* deg  = (int*)d_ws;
    int* offs = deg + N_NODES;
    int* pos  = offs + N_NODES + 1;
    int* csr  = pos + N_NODES;
    int* bsum = csr + N_EDGES;
    int* bpre = bsum + NB;

    hipMemsetAsync(deg, 0, (size_t)N_NODES * 4, stream);
    hist_kernel<<<(N_EDGES + 255) / 256, 256, 0, stream>>>(ei, deg);
    scanA_kernel<<<NB, 256, 0, stream>>>(deg, bsum);
    scanB_kernel<<<1, 256, 0, stream>>>(bsum, bpre, offs);
    scanC_kernel<<<NB, 256, 0, stream>>>(deg, bpre, offs, pos);
    fill_kernel<<<(N_EDGES + 255) / 256, 256, 0, stream>>>(ei, pos, csr);

    if (ws_size >= xb_need) {
      // Tier A: bf16-everything fused path.
      unsigned short* Wt1 = (unsigned short*)(bpre + NB);
      unsigned short* Wt2 = Wt1 + HIDDEN * HIDDEN;
      unsigned short* xb  = Wt2 + HIDDEN * HIDDEN;
      const int nprep = (N_NODES * HIDDEN / 8 + 255) / 256;
      prep_kernel<<<nprep, 256, 0, stream>>>(x, W1, W2, xb, Wt1, Wt2);
      fused_xb_kernel<<<(N_NODES + BR - 1) / BR, 256, 0, stream>>>(
          offs, csr, xb, Wt1, Wt2, b1, b2, out);
    } else if (ws_size >= wt_need) {
      // Tier A-old: f32-gather fused path.
      unsigned short* Wt1 = (unsigned short*)(bpre + NB);
      unsigned short* Wt2 = Wt1 + HIDDEN * HIDDEN;
      prep_w<<<(HIDDEN * HIDDEN + 255) / 256, 256, 0, stream>>>(W1, W2, Wt1, Wt2);
      fused_kernel<<<(N_NODES + BR - 1) / BR, 256, 0, stream>>>(
          offs, csr, x, Wt1, Wt2, b1, b2, out);
    } else {
      // Tier B: f32 gather + rlane MLP.
      gather_kernel<<<(N_NODES * 64 + 255) / 256, 256, 0, stream>>>(offs, csr,
                                                                    x, out);
      mlp_kernel<<<256, 512, 0, stream>>>(x, out, W1, b1, W2, b2);
    }
  } else {
    // Tier C: atomic scatter + rlane MLP.
    hipMemsetAsync(out, 0, (size_t)N_NODES * HIDDEN * sizeof(float), stream);
    const long long total = (long long)N_EDGES * 32;
    scatter_kernel<<<(int)((total + 255) / 256), 256, 0, stream>>>(ei, x, out);
    mlp_kernel<<<256, 512, 0, stream>>>(x, out, W1, b1, W2, b2);
  }
}